// Round 1
// baseline (690.014 us; speedup 1.0000x reference)
//
#include <hip/hip_runtime.h>
#include <cstdint>
#include <cstddef>

#define NN 8192
#define HEADS 4
#define JSPLIT 4
#define JCHUNK (NN / JSPLIT)   // 2048

typedef __attribute__((ext_vector_type(4))) float  f4;
typedef __attribute__((ext_vector_type(4))) int    i4;
typedef __attribute__((ext_vector_type(8))) short  short8;
typedef __attribute__((ext_vector_type(4))) unsigned short us4;
typedef __attribute__((ext_vector_type(4))) unsigned int   u4;

__device__ __forceinline__ unsigned short f2bf(float f) {
    unsigned int u = __builtin_bit_cast(unsigned int, f);
    u += 0x7FFFu + ((u >> 16) & 1u);           // RNE
    return (unsigned short)(u >> 16);
}

// ---------------- K0: x -> bf16 (row-major), W -> WT bf16 (transposed) ----
__global__ void k0_convert(const float* __restrict__ x, const float* __restrict__ W,
                           unsigned short* __restrict__ xb, unsigned short* __restrict__ WT) {
    int b = blockIdx.x;
    if (b < 2048) {
        int idx = (b * 256 + threadIdx.x) * 4;
        f4 v = *(const f4*)(x + idx);
        us4 o;
        o.x = f2bf(v.x); o.y = f2bf(v.y); o.z = f2bf(v.z); o.w = f2bf(v.w);
        *(us4*)(xb + idx) = o;
    } else {
        int f = b - 2048;               // 0..255 : input-feature row of W
        int c = threadIdx.x;            // 0..255 : (head*64+d) column
        WT[c * 256 + f] = f2bf(W[f * 256 + c]);
    }
}

// ---------------- K1: h = x*W (bf16 MFMA); writes hT bf16 + sL/dL ---------
// block = 256 thr (4 waves, wave = head). M-tile = 32 rows, N = 64 (head), K = 256.
__global__ __launch_bounds__(256) void k1_hgemm(
    const unsigned short* __restrict__ xb, const unsigned short* __restrict__ WT,
    const float* __restrict__ aS, const float* __restrict__ aD,
    unsigned short* __restrict__ hT, float* __restrict__ sL, float* __restrict__ dL)
{
    const int tid  = threadIdx.x;
    const int head = tid >> 6;
    const int lane = tid & 63;
    const int col  = lane & 15;
    const int quad = lane >> 4;
    const int i0   = blockIdx.x * 32;

    const unsigned short* ar0 = xb + (size_t)(i0 + col) * 256 + quad * 8;
    const unsigned short* ar1 = ar0 + 16 * 256;
    const unsigned short* br  = WT + (size_t)(head * 64 + col) * 256 + quad * 8;

    f4 C[2][4];
    #pragma unroll
    for (int a = 0; a < 2; a++)
        #pragma unroll
        for (int b = 0; b < 4; b++) C[a][b] = f4{0.f, 0.f, 0.f, 0.f};

    #pragma unroll
    for (int kk = 0; kk < 256; kk += 32) {
        short8 a0 = *(const short8*)(ar0 + kk);
        short8 a1 = *(const short8*)(ar1 + kk);
        #pragma unroll
        for (int nt = 0; nt < 4; nt++) {
            short8 bf = *(const short8*)(br + nt * 16 * 256 + kk);
            C[0][nt] = __builtin_amdgcn_mfma_f32_16x16x32_bf16(a0, bf, C[0][nt], 0, 0, 0);
            C[1][nt] = __builtin_amdgcn_mfma_f32_16x16x32_bf16(a1, bf, C[1][nt], 0, 0, 0);
        }
    }

    // ---- src/dst logits (fp32), scaled by log2(e) -------------------------
    float as_[4], ad_[4];
    #pragma unroll
    for (int nt = 0; nt < 4; nt++) {
        as_[nt] = aS[head * 64 + nt * 16 + col];
        ad_[nt] = aD[head * 64 + nt * 16 + col];
    }
    #pragma unroll
    for (int mt = 0; mt < 2; mt++) {
        #pragma unroll
        for (int r = 0; r < 4; r++) {
            float sv = 0.f, dv = 0.f;
            #pragma unroll
            for (int nt = 0; nt < 4; nt++) {
                sv += C[mt][nt][r] * as_[nt];
                dv += C[mt][nt][r] * ad_[nt];
            }
            #pragma unroll
            for (int m = 1; m < 16; m <<= 1) {     // reduce over the 16 cols
                sv += __shfl_xor(sv, m, 64);
                dv += __shfl_xor(dv, m, 64);
            }
            if (col == 0) {
                int i = i0 + mt * 16 + quad * 4 + r;
                sL[head * NN + i] = sv * 1.4426950408889634f;
                dL[head * NN + i] = dv * 1.4426950408889634f;
            }
        }
    }

    // ---- hT (bf16, [256][8192]) ------------------------------------------
    #pragma unroll
    for (int mt = 0; mt < 2; mt++) {
        #pragma unroll
        for (int nt = 0; nt < 4; nt++) {
            us4 pk;
            pk.x = f2bf(C[mt][nt][0]); pk.y = f2bf(C[mt][nt][1]);
            pk.z = f2bf(C[mt][nt][2]); pk.w = f2bf(C[mt][nt][3]);
            *(us4*)(hT + (size_t)(head * 64 + nt * 16 + col) * NN
                        + i0 + mt * 16 + quad * 4) = pk;
        }
    }
}

// ---------------- K2: fused masked softmax-weight + aggregation ----------
__device__ __forceinline__ short8 build_w(const i4& aa, const i4& ab,
                                          const f4& d0, const f4& d1,
                                          float s, float s02) {
    float dd[8] = {d0[0], d0[1], d0[2], d0[3], d1[0], d1[1], d1[2], d1[3]};
    int   ad[8] = {aa[0], aa[1], aa[2], aa[3], ab[0], ab[1], ab[2], ab[3]};
    float e[8];
    #pragma unroll
    for (int t = 0; t < 8; t++) {
        float z  = s + dd[t];                       // (s+d)*log2e
        float zl = fmaf(0.2f, dd[t], s02);          // 0.2*(s+d)*log2e
        float m  = fmaxf(z, zl);                    // leaky in log2 domain
        float ev = __builtin_amdgcn_exp2f(m);
        e[t] = (ad[t] != 0) ? ev : 0.0f;
    }
    u4 pv;
    #pragma unroll
    for (int t = 0; t < 4; t++) {
        unsigned int b0 = __builtin_bit_cast(unsigned int, e[2 * t]);
        unsigned int b1 = __builtin_bit_cast(unsigned int, e[2 * t + 1]);
        pv[t] = ((b0 + 0x8000u) >> 16) | ((b1 + 0x8000u) & 0xFFFF0000u);
    }
    return __builtin_bit_cast(short8, pv);
}

// grid = 256 i-tiles * 4 j-splits; block = 256 thr (wave = head, all 4 heads
// share one block so adj is fetched once and L1-broadcast across heads).
__global__ __launch_bounds__(256) void k2_gat(
    const int* __restrict__ adj, const unsigned short* __restrict__ hT,
    const float* __restrict__ sL, const float* __restrict__ dL,
    float* __restrict__ Pout, float* __restrict__ PS)
{
    const int tid   = threadIdx.x;
    const int head  = tid >> 6;
    const int lane  = tid & 63;
    const int col   = lane & 15;
    const int quad  = lane >> 4;
    const int itile = blockIdx.x & 255;
    const int split = blockIdx.x >> 8;
    const int i0    = itile * 32;
    const int j0    = split * JCHUNK;

    const float s0  = sL[head * NN + i0 + col];
    const float s1  = sL[head * NN + i0 + 16 + col];
    const float s0h = 0.2f * s0;
    const float s1h = 0.2f * s1;

    const int* arow0 = adj + (size_t)(i0 + col) * NN + j0 + quad * 8;
    const int* arow1 = arow0 + (size_t)16 * NN;
    const float* drow = dL + head * NN + j0 + quad * 8;
    const unsigned short* brow = hT + (size_t)(head * 64 + col) * NN + j0 + quad * 8;

    f4 acc[2][4];
    f4 accS[2];
    #pragma unroll
    for (int a = 0; a < 2; a++) {
        accS[a] = f4{0.f, 0.f, 0.f, 0.f};
        #pragma unroll
        for (int b = 0; b < 4; b++) acc[a][b] = f4{0.f, 0.f, 0.f, 0.f};
    }
    short8 ones;
    #pragma unroll
    for (int t = 0; t < 8; t++) ones[t] = (short)0x3F80;   // bf16 1.0

    #pragma unroll 2
    for (int jj = 0; jj < JCHUNK; jj += 32) {
        i4 a0a = *(const i4*)(arow0 + jj);
        i4 a0b = *(const i4*)(arow0 + jj + 4);
        i4 a1a = *(const i4*)(arow1 + jj);
        i4 a1b = *(const i4*)(arow1 + jj + 4);
        f4 d0  = *(const f4*)(drow + jj);
        f4 d1  = *(const f4*)(drow + jj + 4);
        short8 B0 = *(const short8*)(brow + jj);
        short8 B1 = *(const short8*)(brow + 16 * NN + jj);
        short8 B2 = *(const short8*)(brow + 32 * NN + jj);
        short8 B3 = *(const short8*)(brow + 48 * NN + jj);

        short8 af0 = build_w(a0a, a0b, d0, d1, s0, s0h);
        short8 af1 = build_w(a1a, a1b, d0, d1, s1, s1h);

        acc[0][0] = __builtin_amdgcn_mfma_f32_16x16x32_bf16(af0, B0, acc[0][0], 0, 0, 0);
        acc[0][1] = __builtin_amdgcn_mfma_f32_16x16x32_bf16(af0, B1, acc[0][1], 0, 0, 0);
        acc[0][2] = __builtin_amdgcn_mfma_f32_16x16x32_bf16(af0, B2, acc[0][2], 0, 0, 0);
        acc[0][3] = __builtin_amdgcn_mfma_f32_16x16x32_bf16(af0, B3, acc[0][3], 0, 0, 0);
        accS[0]   = __builtin_amdgcn_mfma_f32_16x16x32_bf16(af0, ones, accS[0], 0, 0, 0);
        acc[1][0] = __builtin_amdgcn_mfma_f32_16x16x32_bf16(af1, B0, acc[1][0], 0, 0, 0);
        acc[1][1] = __builtin_amdgcn_mfma_f32_16x16x32_bf16(af1, B1, acc[1][1], 0, 0, 0);
        acc[1][2] = __builtin_amdgcn_mfma_f32_16x16x32_bf16(af1, B2, acc[1][2], 0, 0, 0);
        acc[1][3] = __builtin_amdgcn_mfma_f32_16x16x32_bf16(af1, B3, acc[1][3], 0, 0, 0);
        accS[1]   = __builtin_amdgcn_mfma_f32_16x16x32_bf16(af1, ones, accS[1], 0, 0, 0);
    }

    // ---- store partials ---------------------------------------------------
    #pragma unroll
    for (int mt = 0; mt < 2; mt++) {
        #pragma unroll
        for (int nt = 0; nt < 4; nt++) {
            #pragma unroll
            for (int r = 0; r < 4; r++) {
                int row = i0 + mt * 16 + quad * 4 + r;
                Pout[((size_t)split * NN + row) * 256 + head * 64 + nt * 16 + col] =
                    acc[mt][nt][r];
            }
        }
        if (col == 0) {
            #pragma unroll
            for (int r = 0; r < 4; r++) {
                int row = i0 + mt * 16 + quad * 4 + r;
                PS[((size_t)split * NN + row) * HEADS + head] = accS[mt][r];
            }
        }
    }
}

// ---------------- K3: reduce splits, normalize, add bias ------------------
__global__ void k3_norm(const float* __restrict__ Pout, const float* __restrict__ PS,
                        const float* __restrict__ bias, float* __restrict__ out)
{
    int t  = blockIdx.x * 256 + threadIdx.x;   // 0..524287
    int c4 = t * 4;
    int i    = c4 >> 8;
    int cb   = c4 & 255;
    int head = cb >> 6;
    f4 num = f4{0.f, 0.f, 0.f, 0.f};
    float den = 0.f;
    #pragma unroll
    for (int s = 0; s < JSPLIT; s++) {
        num += *(const f4*)(Pout + ((size_t)s * NN + i) * 256 + cb);
        den += PS[((size_t)s * NN + i) * HEADS + head];
    }
    f4 bv = *(const f4*)(bias + cb);
    f4 o  = num * (1.0f / den) + bv;
    *(f4*)(out + c4) = o;
}

extern "C" void kernel_launch(void* const* d_in, const int* in_sizes, int n_in,
                              void* d_out, int out_size, void* d_ws, size_t ws_size,
                              hipStream_t stream) {
    (void)in_sizes; (void)n_in; (void)out_size; (void)ws_size;
    const float* x    = (const float*)d_in[0];
    const int*   adj  = (const int*)d_in[1];
    const float* W    = (const float*)d_in[2];
    const float* aS   = (const float*)d_in[3];
    const float* aD   = (const float*)d_in[4];
    const float* bias = (const float*)d_in[5];
    float* out = (float*)d_out;

    char* ws = (char*)d_ws;
    unsigned short* xb = (unsigned short*)(ws);             //  4,194,304 B
    unsigned short* WT = (unsigned short*)(ws + 4194304);   //    131,072 B
    unsigned short* hT = (unsigned short*)(ws + 4325376);   //  4,194,304 B
    float* sL   = (float*)(ws + 8519680);                   //    131,072 B
    float* dL   = (float*)(ws + 8650752);                   //    131,072 B
    float* Pout = (float*)(ws + 8781824);                   // 33,554,432 B
    float* PS   = (float*)(ws + 42336256);                  //    524,288 B
    // total ws use: 42,860,544 B

    k0_convert<<<2304, 256, 0, stream>>>(x, W, xb, WT);
    k1_hgemm<<<256, 256, 0, stream>>>(xb, WT, aS, aD, hT, sL, dL);
    k2_gat<<<1024, 256, 0, stream>>>(adj, hT, sL, dL, Pout, PS);
    k3_norm<<<2048, 256, 0, stream>>>(Pout, PS, bias, out);
}

// Round 2
// 489.862 us; speedup vs baseline: 1.4086x; 1.4086x over previous
//
#include <hip/hip_runtime.h>
#include <cstdint>
#include <cstddef>

#define NN 8192
#define HEADS 4

typedef __attribute__((ext_vector_type(4))) float  f4;
typedef __attribute__((ext_vector_type(4))) int    i4;
typedef __attribute__((ext_vector_type(8))) short  short8;
typedef __attribute__((ext_vector_type(4))) unsigned short us4;
typedef __attribute__((ext_vector_type(4))) unsigned int   u4;
typedef unsigned int   uint32;
typedef unsigned short ushort16_t;

__device__ __forceinline__ unsigned short f2bf(float f) {
    unsigned int u = __builtin_bit_cast(unsigned int, f);
    u += 0x7FFFu + ((u >> 16) & 1u);           // RNE
    return (unsigned short)(u >> 16);
}

// ---------------- K0: x -> bf16 (row-major), W -> WT bf16 (transposed) ----
__global__ void k0_convert(const float* __restrict__ x, const float* __restrict__ W,
                           unsigned short* __restrict__ xb, unsigned short* __restrict__ WT) {
    int b = blockIdx.x;
    if (b < 2048) {
        int idx = (b * 256 + threadIdx.x) * 4;
        f4 v = *(const f4*)(x + idx);
        us4 o;
        o.x = f2bf(v.x); o.y = f2bf(v.y); o.z = f2bf(v.z); o.w = f2bf(v.w);
        *(us4*)(xb + idx) = o;
    } else {
        int f = b - 2048;               // 0..255 : input-feature row of W
        int c = threadIdx.x;            // 0..255 : (head*64+d) column
        WT[c * 256 + f] = f2bf(W[f * 256 + c]);
    }
}

// ---------------- Kpack: adj int32 -> 1 bit, [N][256] words ---------------
// thread t packs word t: bits n = adj[t*32 + n]
__global__ __launch_bounds__(256) void kpack(const int* __restrict__ adj,
                                             uint32* __restrict__ adjP) {
    int gid = blockIdx.x * 256 + threadIdx.x;       // 0 .. 2M-1
    const int* p = adj + (size_t)gid * 32;
    uint32 w = 0;
    #pragma unroll
    for (int k = 0; k < 8; k++) {
        i4 v = *(const i4*)(p + k * 4);
        w |= (v.x != 0 ? 1u : 0u) << (k * 4 + 0);
        w |= (v.y != 0 ? 1u : 0u) << (k * 4 + 1);
        w |= (v.z != 0 ? 1u : 0u) << (k * 4 + 2);
        w |= (v.w != 0 ? 1u : 0u) << (k * 4 + 3);
    }
    adjP[gid] = w;
}

// ---------------- K1: h = x*W (bf16 MFMA) -> hF (B-frag order) + exp tables
// block = 256 thr (4 waves, wave = head). M-tile = 32 rows, N = 64, K = 256.
// hF layout: frag(jb, head, nt)[lane*8 + t], frag stride 512 shorts.
__global__ __launch_bounds__(256) void k1_hgemm(
    const unsigned short* __restrict__ xb, const unsigned short* __restrict__ WT,
    const float* __restrict__ aS, const float* __restrict__ aD,
    unsigned short* __restrict__ hF,
    float* __restrict__ sE, float* __restrict__ sE2,
    float* __restrict__ dE, float* __restrict__ dE2)
{
    const int tid  = threadIdx.x;
    const int head = tid >> 6;
    const int lane = tid & 63;
    const int col  = lane & 15;
    const int quad = lane >> 4;
    const int i0   = blockIdx.x * 32;

    const unsigned short* ar0 = xb + (size_t)(i0 + col) * 256 + quad * 8;
    const unsigned short* ar1 = ar0 + 16 * 256;
    const unsigned short* br  = WT + (size_t)(head * 64 + col) * 256 + quad * 8;

    f4 C[2][4];
    #pragma unroll
    for (int a = 0; a < 2; a++)
        #pragma unroll
        for (int b = 0; b < 4; b++) C[a][b] = f4{0.f, 0.f, 0.f, 0.f};

    #pragma unroll
    for (int kk = 0; kk < 256; kk += 32) {
        short8 a0 = *(const short8*)(ar0 + kk);
        short8 a1 = *(const short8*)(ar1 + kk);
        #pragma unroll
        for (int nt = 0; nt < 4; nt++) {
            short8 bf = *(const short8*)(br + nt * 16 * 256 + kk);
            C[0][nt] = __builtin_amdgcn_mfma_f32_16x16x32_bf16(a0, bf, C[0][nt], 0, 0, 0);
            C[1][nt] = __builtin_amdgcn_mfma_f32_16x16x32_bf16(a1, bf, C[1][nt], 0, 0, 0);
        }
    }

    // ---- src/dst logit exps ----------------------------------------------
    float as_[4], ad_[4];
    #pragma unroll
    for (int nt = 0; nt < 4; nt++) {
        as_[nt] = aS[head * 64 + nt * 16 + col];
        ad_[nt] = aD[head * 64 + nt * 16 + col];
    }
    #pragma unroll
    for (int mt = 0; mt < 2; mt++) {
        #pragma unroll
        for (int r = 0; r < 4; r++) {
            float sv = 0.f, dv = 0.f;
            #pragma unroll
            for (int nt = 0; nt < 4; nt++) {
                sv += C[mt][nt][r] * as_[nt];
                dv += C[mt][nt][r] * ad_[nt];
            }
            #pragma unroll
            for (int m = 1; m < 16; m <<= 1) {     // reduce over the 16 cols
                sv += __shfl_xor(sv, m, 64);
                dv += __shfl_xor(dv, m, 64);
            }
            if (col == 0) {
                int i = i0 + mt * 16 + quad * 4 + r;
                float zs = sv * 1.4426950408889634f;   // log2(e) folded
                float zd = dv * 1.4426950408889634f;
                sE [head * NN + i] = __builtin_amdgcn_exp2f(zs);
                sE2[head * NN + i] = __builtin_amdgcn_exp2f(0.2f * zs);
                dE [head * NN + i] = __builtin_amdgcn_exp2f(zd);
                dE2[head * NN + i] = __builtin_amdgcn_exp2f(0.2f * zd);
            }
        }
    }

    // ---- hF scatter into B-fragment order --------------------------------
    // target: frag(jb=blockIdx, head, nt), lane' = q'*16+col, elem t
    const size_t fbase = (((size_t)blockIdx.x * HEADS + head) * 4) * 512;
    #pragma unroll
    for (int mt = 0; mt < 2; mt++) {
        #pragma unroll
        for (int nt = 0; nt < 4; nt++) {
            #pragma unroll
            for (int r = 0; r < 4; r++) {
                int il = mt * 16 + quad * 4 + r;      // j-local 0..31
                int qp = il >> 3;
                int t  = il & 7;
                hF[fbase + (size_t)nt * 512 + (qp * 16 + col) * 8 + t] =
                    f2bf(C[mt][nt][r]);
            }
        }
    }
}

// ---------------- K2: fused masked softmax-weight + aggregation ----------
__device__ __forceinline__ short8 build_w(uint32 bits,
                                          const f4& alo, const f4& ahi,
                                          const f4& blo, const f4& bhi,
                                          float es, float es2) {
    float aa[8] = {alo[0], alo[1], alo[2], alo[3], ahi[0], ahi[1], ahi[2], ahi[3]};
    float bb[8] = {blo[0], blo[1], blo[2], blo[3], bhi[0], bhi[1], bhi[2], bhi[3]};
    float e[8];
    #pragma unroll
    for (int t = 0; t < 8; t++) {
        float av = es  * aa[t];
        float bv = es2 * bb[t];
        float m  = fmaxf(av, bv);                 // exp2(leaky) via monotonicity
        float mf = (float)((bits >> t) & 1u);
        e[t] = m * mf;
    }
    u4 pv;
    #pragma unroll
    for (int t = 0; t < 4; t++) {
        uint32 e0 = __builtin_bit_cast(uint32, e[2 * t])     + 0x8000u;
        uint32 e1 = __builtin_bit_cast(uint32, e[2 * t + 1]) + 0x8000u;
        pv[t] = __builtin_amdgcn_perm(e1, e0, 0x07060302u);  // [hi16(e1):hi16(e0)]
    }
    return __builtin_bit_cast(short8, pv);
}

// grid = 256 i-tiles * jsplit; block = 256 thr (wave = head).
__global__ __launch_bounds__(256, 4) void k2_gat(
    const uint32* __restrict__ adjP, const unsigned short* __restrict__ hF,
    const float* __restrict__ sE, const float* __restrict__ sE2,
    const float* __restrict__ dE, const float* __restrict__ dE2,
    float* __restrict__ Pout, float* __restrict__ PS, int jchunk)
{
    const int tid   = threadIdx.x;
    const int head  = tid >> 6;
    const int lane  = tid & 63;
    const int col   = lane & 15;
    const int quad  = lane >> 4;
    const int itile = blockIdx.x & 255;
    const int split = blockIdx.x >> 8;
    const int i0    = itile * 32;
    const int j0    = split * jchunk;

    const float es0  = sE [head * NN + i0 + col];
    const float es0b = sE2[head * NN + i0 + col];
    const float es1  = sE [head * NN + i0 + 16 + col];
    const float es1b = sE2[head * NN + i0 + 16 + col];

    const uint32* ap0 = adjP + (size_t)(i0 + col) * 256 + (j0 >> 5);
    const uint32* ap1 = ap0 + 16 * 256;
    const float* dEp  = dE  + head * NN + j0 + quad * 8;
    const float* dE2p = dE2 + head * NN + j0 + quad * 8;
    const unsigned short* hbase =
        hF + ((size_t)(j0 >> 5) * HEADS + head) * 4 * 512 + lane * 8;

    f4 acc[2][4];
    f4 accS[2];
    #pragma unroll
    for (int a = 0; a < 2; a++) {
        accS[a] = f4{0.f, 0.f, 0.f, 0.f};
        #pragma unroll
        for (int b = 0; b < 4; b++) acc[a][b] = f4{0.f, 0.f, 0.f, 0.f};
    }
    short8 ones;
    #pragma unroll
    for (int t = 0; t < 8; t++) ones[t] = (short)0x3F80;   // bf16 1.0

    const int ngrp = jchunk >> 7;             // 128 j per group
    for (int g = 0; g < ngrp; ++g) {
        u4 aw0 = *(const u4*)(ap0 + g * 4);
        u4 aw1 = *(const u4*)(ap1 + g * 4);
        #pragma unroll
        for (int k = 0; k < 4; ++k) {
            const int jb = g * 4 + k;         // local 32-j block
            const float* dp  = dEp  + jb * 32;
            const float* dp2 = dE2p + jb * 32;
            f4 alo = *(const f4*)(dp);
            f4 ahi = *(const f4*)(dp + 4);
            f4 blo = *(const f4*)(dp2);
            f4 bhi = *(const f4*)(dp2 + 4);
            const unsigned short* hp = hbase + (size_t)jb * (HEADS * 4 * 512);
            short8 B0 = *(const short8*)(hp);
            short8 B1 = *(const short8*)(hp + 512);
            short8 B2 = *(const short8*)(hp + 1024);
            short8 B3 = *(const short8*)(hp + 1536);

            uint32 b0 = (aw0[k] >> (quad * 8)) & 0xFFu;
            uint32 b1 = (aw1[k] >> (quad * 8)) & 0xFFu;
            short8 af0 = build_w(b0, alo, ahi, blo, bhi, es0, es0b);
            short8 af1 = build_w(b1, alo, ahi, blo, bhi, es1, es1b);

            acc[0][0] = __builtin_amdgcn_mfma_f32_16x16x32_bf16(af0, B0, acc[0][0], 0, 0, 0);
            acc[0][1] = __builtin_amdgcn_mfma_f32_16x16x32_bf16(af0, B1, acc[0][1], 0, 0, 0);
            acc[0][2] = __builtin_amdgcn_mfma_f32_16x16x32_bf16(af0, B2, acc[0][2], 0, 0, 0);
            acc[0][3] = __builtin_amdgcn_mfma_f32_16x16x32_bf16(af0, B3, acc[0][3], 0, 0, 0);
            accS[0]   = __builtin_amdgcn_mfma_f32_16x16x32_bf16(af0, ones, accS[0], 0, 0, 0);
            acc[1][0] = __builtin_amdgcn_mfma_f32_16x16x32_bf16(af1, B0, acc[1][0], 0, 0, 0);
            acc[1][1] = __builtin_amdgcn_mfma_f32_16x16x32_bf16(af1, B1, acc[1][1], 0, 0, 0);
            acc[1][2] = __builtin_amdgcn_mfma_f32_16x16x32_bf16(af1, B2, acc[1][2], 0, 0, 0);
            acc[1][3] = __builtin_amdgcn_mfma_f32_16x16x32_bf16(af1, B3, acc[1][3], 0, 0, 0);
            accS[1]   = __builtin_amdgcn_mfma_f32_16x16x32_bf16(af1, ones, accS[1], 0, 0, 0);
        }
    }

    // ---- store partials ---------------------------------------------------
    #pragma unroll
    for (int mt = 0; mt < 2; mt++) {
        #pragma unroll
        for (int nt = 0; nt < 4; nt++) {
            #pragma unroll
            for (int r = 0; r < 4; r++) {
                int row = i0 + mt * 16 + quad * 4 + r;
                Pout[((size_t)split * NN + row) * 256 + head * 64 + nt * 16 + col] =
                    acc[mt][nt][r];
            }
        }
        if (col == 0) {
            #pragma unroll
            for (int r = 0; r < 4; r++) {
                int row = i0 + mt * 16 + quad * 4 + r;
                PS[((size_t)split * NN + row) * HEADS + head] = accS[mt][r];
            }
        }
    }
}

// ---------------- K3: reduce splits, normalize, add bias ------------------
__global__ void k3_norm(const float* __restrict__ Pout, const float* __restrict__ PS,
                        const float* __restrict__ bias, float* __restrict__ out,
                        int jsplit)
{
    int t  = blockIdx.x * 256 + threadIdx.x;   // 0..524287
    int c4 = t * 4;
    int i    = c4 >> 8;
    int cb   = c4 & 255;
    int head = cb >> 6;
    f4 num = f4{0.f, 0.f, 0.f, 0.f};
    float den = 0.f;
    for (int s = 0; s < jsplit; s++) {
        num += *(const f4*)(Pout + ((size_t)s * NN + i) * 256 + cb);
        den += PS[((size_t)s * NN + i) * HEADS + head];
    }
    f4 bv = *(const f4*)(bias + cb);
    f4 o  = num * (1.0f / den) + bv;
    *(f4*)(out + c4) = o;
}

extern "C" void kernel_launch(void* const* d_in, const int* in_sizes, int n_in,
                              void* d_out, int out_size, void* d_ws, size_t ws_size,
                              hipStream_t stream) {
    (void)in_sizes; (void)n_in; (void)out_size;
    const float* x    = (const float*)d_in[0];
    const int*   adj  = (const int*)d_in[1];
    const float* W    = (const float*)d_in[2];
    const float* aS   = (const float*)d_in[3];
    const float* aD   = (const float*)d_in[4];
    const float* bias = (const float*)d_in[5];
    float* out = (float*)d_out;

    char* ws = (char*)d_ws;
    unsigned short* xb = (unsigned short*)(ws);              //  4 MB
    unsigned short* WT = (unsigned short*)(ws +  4194304);   //  128 KB
    unsigned short* hF = (unsigned short*)(ws +  4325376);   //  4 MB
    float*  sE   = (float*)(ws +  8519680);                  //  128 KB
    float*  sE2  = (float*)(ws +  8650752);                  //  128 KB
    float*  dE   = (float*)(ws +  8781824);                  //  128 KB
    float*  dE2  = (float*)(ws +  8912896);                  //  128 KB
    uint32* adjP = (uint32*)(ws +  9043968);                 //  8 MB
    float*  PS   = (float*)(ws + 17432576);                  //  up to 1 MB
    float*  Pout = (float*)(ws + 18481152);                  //  jsplit * 8 MB

    const size_t need8 = 18481152ull + 8ull * 8388608ull;
    const int jsplit = (ws_size >= need8) ? 8 : 4;
    const int jchunk = NN / jsplit;

    k0_convert<<<2304, 256, 0, stream>>>(x, W, xb, WT);
    kpack<<<8192, 256, 0, stream>>>(adj, adjP);
    k1_hgemm<<<256, 256, 0, stream>>>(xb, WT, aS, aD, hF, sE, sE2, dE, dE2);
    k2_gat<<<256 * jsplit, 256, 0, stream>>>(adjP, hF, sE, sE2, dE, dE2, Pout, PS, jchunk);
    k3_norm<<<2048, 256, 0, stream>>>(Pout, PS, bias, out, jsplit);
}